// Round 20
// baseline (150.867 us; speedup 1.0000x reference)
//
#include <hip/hip_runtime.h>
#include <hip/hip_fp16.h>

#define N_NODES 100000
#define N_EDGES 1600000
#define DIM 128
#define NBUK 1563     // ceil(N_NODES / 64), bucket = dst >> 6
#define EPB 4096      // edges per block in hist / scatter
#define NBLK 391      // ceil(N_EDGES / EPB)
#define NCNT (NBUK * NBLK)   // 611133 (bucket,block) counters
#define NSC 299       // ceil(NCNT / 2048) scan blocks
#define CAPB 1536     // max edges per bucket (mean 1024, +16 sigma)
#define EPT 6         // max edges per thread in sort_gather

typedef __attribute__((ext_vector_type(4))) float f32x4;
typedef _Float16 h2 __attribute__((ext_vector_type(2)));
typedef _Float16 h8v __attribute__((ext_vector_type(8)));

__device__ __forceinline__ unsigned short f2h16(float f) {
    return __half_as_ushort(__float2half(f));
}

// ---------------------------------------------------------------------------
// 1) per-block bucket histogram + x->fp16 conversion (merged)
// ---------------------------------------------------------------------------
__global__ __launch_bounds__(256) void hist2_conv(
    const int* __restrict__ ei, int* __restrict__ cnts,
    const float* __restrict__ x, ushort* __restrict__ xh, int do_conv)
{
    __shared__ int cnt[NBUK];
    for (int i = threadIdx.x; i < NBUK; i += 256) cnt[i] = 0;

    if (do_conv) {
        for (int i = blockIdx.x * 256 + threadIdx.x; i < N_NODES * DIM / 4;
             i += NBLK * 256) {
            float4 v = ((const float4*)x)[i];
            ushort4 o;
            o.x = f2h16(v.x);
            o.y = f2h16(v.y);
            o.z = f2h16(v.z);
            o.w = f2h16(v.w);
            ((ushort4*)xh)[i] = o;
        }
    }
    __syncthreads();

    int e0 = blockIdx.x * EPB;
    int e1 = min(e0 + EPB, N_EDGES);
    for (int e = e0 + threadIdx.x; e < e1; e += 256)
        atomicAdd(&cnt[ei[N_EDGES + e] >> 6], 1);
    __syncthreads();
    for (int b = threadIdx.x; b < NBUK; b += 256)
        cnts[b * NBLK + blockIdx.x] = cnt[b];
}

// ---------------------------------------------------------------------------
// 2) scanA: per-2048-chunk exclusive scan, block sums -> bsums (raw)
// ---------------------------------------------------------------------------
__global__ __launch_bounds__(256) void scanA(
    int* __restrict__ cnts, int* __restrict__ bsums)
{
    __shared__ int s[256];
    int t = threadIdx.x;
    int base = blockIdx.x * 2048 + t * 8;
    int v[8], sum = 0;
    #pragma unroll
    for (int j = 0; j < 8; ++j) {
        v[j] = (base + j < NCNT) ? cnts[base + j] : 0;
        sum += v[j];
    }
    s[t] = sum;
    __syncthreads();
    for (int off = 1; off < 256; off <<= 1) {
        int xg = (t >= off) ? s[t - off] : 0;
        __syncthreads();
        s[t] += xg;
        __syncthreads();
    }
    int excl = s[t] - sum;
    #pragma unroll
    for (int j = 0; j < 8; ++j) {
        if (base + j < NCNT) cnts[base + j] = excl;
        excl += v[j];
    }
    if (t == 255) bsums[blockIdx.x] = s[255];
}

// ---------------------------------------------------------------------------
// scanC + folded scanB + prep_w (fp16 fragment layout). 512 threads.
// ---------------------------------------------------------------------------
__global__ __launch_bounds__(512) void scanC_prepw(
    int* __restrict__ ebase, const int* __restrict__ bsums, int* __restrict__ bk,
    const float* __restrict__ W1, const float* __restrict__ W2,
    ushort* __restrict__ wf1, ushort* __restrict__ wf2)
{
    __shared__ int s[512];
    __shared__ int ex[512];
    int t = threadIdx.x;
    int v = (t < NSC) ? bsums[t] : 0;
    s[t] = v;
    __syncthreads();
    for (int off = 1; off < 512; off <<= 1) {
        int xg = (t >= off) ? s[t - off] : 0;
        __syncthreads();
        s[t] += xg;
        __syncthreads();
    }
    ex[t] = s[t] - v;   // exclusive prefix of bsums
    __syncthreads();

    int i = blockIdx.x * 512 + t;
    if (i < NCNT) {
        int val = ebase[i] + ex[i >> 11];
        ebase[i] = val;
        if (i % NBLK == 0) bk[i / NBLK] = val;   // bucket base
    }
    if (i == 0) bk[NBUK] = N_EDGES;

    if (i < DIM * DIM) {   // prep_w: fp16 fragment layout
        int lane = (i >> 3) & 63;
        int j = i & 7;
        int frag = i >> 9;
        int kt = frag >> 3, nt = frag & 7;
        int k = kt * 32 + (lane >> 4) * 8 + j;
        int n = nt * 16 + (lane & 15);
        wf1[i] = f2h16(W1[k * DIM + n]);
        wf2[i] = f2h16(W2[k * DIM + n]);
    }
}

// ---------------------------------------------------------------------------
// 3) scatter: payload = src | attr<<17 | dst_local<<19 (6 bits)
// ---------------------------------------------------------------------------
__global__ __launch_bounds__(256) void pass2_scatter(
    const int* __restrict__ ei, const int* __restrict__ ea,
    const int* __restrict__ ebase, int* __restrict__ ebuf)
{
    __shared__ int cnt[NBUK];
    __shared__ int mybase[NBUK];
    for (int i = threadIdx.x; i < NBUK; i += 256) {
        cnt[i] = 0;
        mybase[i] = ebase[i * NBLK + blockIdx.x];
    }
    __syncthreads();
    int e0 = blockIdx.x * EPB;
    int e1 = min(e0 + EPB, N_EDGES);
    for (int e = e0 + threadIdx.x; e < e1; e += 256) {
        int src = ei[e];
        int dst = ei[N_EDGES + e];
        int at  = ea[e];
        int pay = src | (at << 17) | ((dst & 63) << 19);
        int b   = dst >> 6;
        int r   = atomicAdd(&cnt[b], 1);
        ebuf[mybase[b] + r] = pay;
    }
}

// ---------------------------------------------------------------------------
// 4) FUSED per-bucket sort + gather. 64-node buckets, 256-thread blocks:
// ~9KB LDS + 256 thr -> up to 8 blocks/CU, grid 1563 (~6 resident/CU).
// ---------------------------------------------------------------------------
template<int HI>
__device__ __forceinline__ float h2acc(h2 m2, float acc) {
#if __has_builtin(__builtin_amdgcn_fdot2)
    h2 b;
    b[0] = (_Float16)(HI ? 0.f : 1.f);
    b[1] = (_Float16)(HI ? 1.f : 0.f);
    return __builtin_amdgcn_fdot2(m2, b, acc, false);
#else
    return acc + (float)m2[HI];
#endif
}

__device__ __forceinline__ void edge_acc(
    int pkv, int c, const unsigned* embh, float* acc, uint4 xv)
{
    const uint4 ev = *(const uint4*)&embh[((((unsigned)pkv >> 17) & 3) << 6) | (c << 2)];
    unsigned xs[4] = {xv.x, xv.y, xv.z, xv.w};
    unsigned es[4] = {ev.x, ev.y, ev.z, ev.w};
    const h2 z2 = (h2)(_Float16)0;
    #pragma unroll
    for (int j = 0; j < 4; ++j) {
        h2 a = __builtin_bit_cast(h2, xs[j]);
        h2 b = __builtin_bit_cast(h2, es[j]);
        h2 m2 = __builtin_elementwise_max(a + b, z2);
        acc[2 * j]     = h2acc<0>(m2, acc[2 * j]);
        acc[2 * j + 1] = h2acc<1>(m2, acc[2 * j + 1]);
    }
}

template<int USE16>
__global__ __launch_bounds__(256) void sort_gather(
    const int* __restrict__ bk, const int* __restrict__ ebuf,
    const float* __restrict__ x, const ushort* __restrict__ xh,
    const float* __restrict__ emb, const float* __restrict__ eps_p,
    ushort* __restrict__ hb)
{
    __shared__ int col_l[CAPB];        // 6KB
    __shared__ int deg[64], sc[64], cur[64];
    __shared__ unsigned embh[256];     // 1KB (USE16)
    __shared__ float femb[512];        // 2KB (fallback)

    const int b = blockIdx.x;
    const int t = threadIdx.x;
    const int lo = bk[b];
    const int n_e = min(bk[b + 1] - lo, CAPB);

    {
        float2 f = ((const float2*)emb)[t];
        if (USE16) {
            __half2 h = __floats2half2_rn(f.x, f.y);
            embh[t] = __builtin_bit_cast(unsigned, h);
        } else {
            femb[2 * t] = f.x;
            femb[2 * t + 1] = f.y;
        }
    }
    if (t < 64) deg[t] = 0;
    __syncthreads();

    // stage this thread's edges in registers (static indexing)
    int er[EPT];
    #pragma unroll
    for (int j = 0; j < EPT; ++j) {
        int i = t + j * 256;
        er[j] = (i < n_e) ? ebuf[lo + i] : -1;
    }

    // pass 1: histogram from registers
    #pragma unroll
    for (int j = 0; j < EPT; ++j)
        if (er[j] != -1)
            atomicAdd(&deg[((unsigned)er[j] >> 19) & 63], 1);
    __syncthreads();

    if (t < 64) sc[t] = deg[t];
    __syncthreads();
    for (int off = 1; off < 64; off <<= 1) {
        int v = 0;
        if (t < 64 && t >= off) v = sc[t - off];
        __syncthreads();
        if (t < 64) sc[t] += v;
        __syncthreads();
    }
    if (t < 64) cur[t] = sc[t] - deg[t];
    __syncthreads();

    // pass 2: scatter from registers into node-sorted LDS list
    #pragma unroll
    for (int j = 0; j < EPT; ++j)
        if (er[j] != -1) {
            int p = atomicAdd(&cur[((unsigned)er[j] >> 19) & 63], 1);
            col_l[p] = er[j];
        }
    __syncthreads();

    // ---- gather: 16 groups x 16 lanes, 4 nodes per group ----
    const int g = t >> 4, c = t & 15;
    const float epsv = 1.0f + eps_p[0];

    for (int ln = g; ln < 64; ln += 16) {
        int n = b * 64 + ln;
        if (n >= N_NODES) break;
        int start = sc[ln] - deg[ln], end = sc[ln];
        float acc[8] = {0.f, 0.f, 0.f, 0.f, 0.f, 0.f, 0.f, 0.f};

        if (USE16) {
            int p = start;
            for (; p + 4 <= end; p += 4) {
                int pk[4];
                uint4 xv[4];
                #pragma unroll
                for (int u = 0; u < 4; ++u) pk[u] = col_l[p + u];
                #pragma unroll
                for (int u = 0; u < 4; ++u)
                    xv[u] = ((const uint4*)xh)[((pk[u] & 0x1FFFF) << 4) | c];
                #pragma unroll
                for (int u = 0; u < 4; ++u)
                    edge_acc(pk[u], c, embh, acc, xv[u]);
            }
            for (; p < end; ++p) {
                int pkv = col_l[p];
                uint4 xv = ((const uint4*)xh)[((pkv & 0x1FFFF) << 4) | c];
                edge_acc(pkv, c, embh, acc, xv);
            }
        } else {
            for (int p = start; p < end; ++p) {
                int pk = col_l[p];
                const float* xr = x + (size_t)(pk & 0x1FFFF) * DIM;
                float4 xa = ((const float4*)xr)[c * 2];
                float4 xb = ((const float4*)xr)[c * 2 + 1];
                const float* er2 = &femb[(((unsigned)pk >> 17) & 3) * DIM + c * 8];
                acc[0] += fmaxf(xa.x + er2[0], 0.f);
                acc[1] += fmaxf(xa.y + er2[1], 0.f);
                acc[2] += fmaxf(xa.z + er2[2], 0.f);
                acc[3] += fmaxf(xa.w + er2[3], 0.f);
                acc[4] += fmaxf(xb.x + er2[4], 0.f);
                acc[5] += fmaxf(xb.y + er2[5], 0.f);
                acc[6] += fmaxf(xb.z + er2[6], 0.f);
                acc[7] += fmaxf(xb.w + er2[7], 0.f);
            }
        }

        // self term: from fp16 xh (coalesced 16B read)
        float o[8];
        {
            uint4 xn = ((const uint4*)xh)[((unsigned)n << 4) | c];
            unsigned xs[4] = {xn.x, xn.y, xn.z, xn.w};
            #pragma unroll
            for (int j = 0; j < 4; ++j) {
                h2 a = __builtin_bit_cast(h2, xs[j]);
                o[2 * j]     = epsv * (float)a[0] + acc[2 * j];
                o[2 * j + 1] = epsv * (float)a[1] + acc[2 * j + 1];
            }
        }

        unsigned pw[4];
        #pragma unroll
        for (int j = 0; j < 4; ++j) {
            __half2 hh = __floats2half2_rn(o[2 * j], o[2 * j + 1]);
            pw[j] = __builtin_bit_cast(unsigned, hh);
        }
        ((uint4*)(hb + (size_t)n * DIM))[c] = make_uint4(pw[0], pw[1], pw[2], pw[3]);
    }
}

// ---------------------------------------------------------------------------
// Fused MLP via f16 MFMA: 64-node tile / 256-thread block, 80KB LDS -> 2/CU.
// ---------------------------------------------------------------------------
__global__ __launch_bounds__(256) void fused_mlp(
    const ushort* __restrict__ hb,
    const ushort* __restrict__ wf1, const ushort* __restrict__ wf2,
    const float* __restrict__ b1,
    const float* __restrict__ lng, const float* __restrict__ lnb,
    const float* __restrict__ b2,
    float* __restrict__ out)
{
    __shared__ ushort w1s[DIM * DIM];
    __shared__ ushort w2s[DIM * DIM];
    __shared__ ushort scr[4 * 16 * DIM];

    #pragma unroll
    for (int i = 0; i < 8; ++i) {
        int idx = i * 256 + threadIdx.x;
        ((uint4*)w1s)[idx] = ((const uint4*)wf1)[idx];
        ((uint4*)w2s)[idx] = ((const uint4*)wf2)[idx];
    }
    __syncthreads();

    const int w  = threadIdx.x >> 6;
    const int l  = threadIdx.x & 63;
    const int lc = l & 15;
    const int lr = l >> 4;

    const int rbase = blockIdx.x * 64 + w * 16;
    const int arow = min(rbase + lc, N_NODES - 1);
    const ushort* hp = hb + (size_t)arow * DIM;

    float g[8], bb[8], bi1[8], bi2[8];
    #pragma unroll
    for (int nt = 0; nt < 8; ++nt) {
        g[nt]  = lng[nt * 16 + lc];
        bb[nt] = lnb[nt * 16 + lc];
        bi1[nt] = b1[nt * 16 + lc];
        bi2[nt] = b2[nt * 16 + lc];
    }

    f32x4 acc[8];
    #pragma unroll
    for (int nt = 0; nt < 8; ++nt)
        acc[nt] = (f32x4){bi1[nt], bi1[nt], bi1[nt], bi1[nt]};

    #pragma unroll
    for (int kt = 0; kt < 4; ++kt) {
        h8v a = *(const h8v*)(hp + kt * 32 + lr * 8);
        #pragma unroll
        for (int nt = 0; nt < 8; ++nt) {
            h8v bf = *(const h8v*)&w1s[((kt * 8 + nt) * 64 + l) * 8];
            acc[nt] = __builtin_amdgcn_mfma_f32_16x16x32_f16(a, bf, acc[nt], 0, 0, 0);
        }
    }

    #pragma unroll
    for (int r = 0; r < 4; ++r) {
        float s1 = 0.f, s2 = 0.f;
        #pragma unroll
        for (int nt = 0; nt < 8; ++nt) { float v = acc[nt][r]; s1 += v; s2 += v * v; }
        s1 += __shfl_xor(s1, 1);  s2 += __shfl_xor(s2, 1);
        s1 += __shfl_xor(s1, 2);  s2 += __shfl_xor(s2, 2);
        s1 += __shfl_xor(s1, 4);  s2 += __shfl_xor(s2, 4);
        s1 += __shfl_xor(s1, 8);  s2 += __shfl_xor(s2, 8);
        float mu  = s1 * (1.0f / DIM);
        float var = s2 * (1.0f / DIM) - mu * mu;
        float rsd = rsqrtf(var + 1e-5f);
        int row = lr * 4 + r;
        #pragma unroll
        for (int nt = 0; nt < 8; ++nt) {
            float v = (acc[nt][r] - mu) * rsd * g[nt] + bb[nt];
            v = fmaxf(v, 0.f);
            int cidx = nt * 16 + lc;
            scr[w * 2048 + row * 128 + (((cidx >> 3) ^ row) << 3) + (cidx & 7)]
                = f2h16(v);
        }
    }

    f32x4 acc2[8];
    #pragma unroll
    for (int nt = 0; nt < 8; ++nt)
        acc2[nt] = (f32x4){bi2[nt], bi2[nt], bi2[nt], bi2[nt]};

    #pragma unroll
    for (int kt = 0; kt < 4; ++kt) {
        h8v a2 = *(const h8v*)&scr[w * 2048 + lc * 128 + (((kt * 4 + lr) ^ lc) << 3)];
        #pragma unroll
        for (int nt = 0; nt < 8; ++nt) {
            h8v bf = *(const h8v*)&w2s[((kt * 8 + nt) * 64 + l) * 8];
            acc2[nt] = __builtin_amdgcn_mfma_f32_16x16x32_f16(a2, bf, acc2[nt], 0, 0, 0);
        }
    }

    #pragma unroll
    for (int r = 0; r < 4; ++r) {
        int orow = rbase + lr * 4 + r;
        if (orow < N_NODES) {
            #pragma unroll
            for (int nt = 0; nt < 8; ++nt)
                out[(size_t)orow * DIM + nt * 16 + lc] = acc2[nt][r];
        }
    }
}

extern "C" void kernel_launch(void* const* d_in, const int* in_sizes, int n_in,
                              void* d_out, int out_size, void* d_ws, size_t ws_size,
                              hipStream_t stream) {
    const float* x    = (const float*)d_in[0];
    const int*   ei   = (const int*)d_in[1];
    const int*   ea   = (const int*)d_in[2];
    const float* emb  = (const float*)d_in[3];
    const float* epsp = (const float*)d_in[4];
    const float* W1   = (const float*)d_in[5];
    const float* b1   = (const float*)d_in[6];
    const float* lng  = (const float*)d_in[7];
    const float* lnb  = (const float*)d_in[8];
    const float* W2   = (const float*)d_in[9];
    const float* b2   = (const float*)d_in[10];
    float* out = (float*)d_out;

    // workspace layout (bytes)
    char* ws = (char*)d_ws;
    int* bk     = (int*)(ws);                 // [NBUK+1] = 6256 B
    int* bsums  = (int*)(ws + 8192);          // [NSC]
    ushort* wf1 = (ushort*)(ws + 12288);      // [16384] fp16 W1 frags
    ushort* wf2 = (ushort*)(ws + 45056);      // [16384] fp16 W2 frags
    int* cnts   = (int*)(ws + 81920);         // [NCNT] = 2.44MB (in-place scan)
    int* ebuf   = (int*)(ws + 2621440);       // [N_EDGES] -> ends 9,021,440
    ushort* hb  = (ushort*)(ws + 9021440);    // [N,128] fp16 h plane
    ushort* xh  = (ushort*)(ws + 59225984);   // [N,128] fp16 x
    const size_t NEED = 59225984 + (size_t)N_NODES * DIM * 2;   // ~84.8 MB

    const int use_f16 = (ws_size >= NEED) ? 1 : 0;

    hist2_conv<<<NBLK, 256, 0, stream>>>(ei, cnts, x, xh, use_f16);
    scanA<<<NSC, 256, 0, stream>>>(cnts, bsums);
    scanC_prepw<<<(NCNT + 511) / 512, 512, 0, stream>>>(
        cnts, bsums, bk, W1, W2, wf1, wf2);
    pass2_scatter<<<NBLK, 256, 0, stream>>>(ei, ea, cnts, ebuf);

    if (use_f16) {
        sort_gather<1><<<NBUK, 256, 0, stream>>>(
            bk, ebuf, x, xh, emb, epsp, hb);
    } else {
        sort_gather<0><<<NBUK, 256, 0, stream>>>(
            bk, ebuf, x, xh, emb, epsp, hb);
    }

    fused_mlp<<<(N_NODES + 63) / 64, 256, 0, stream>>>(
        hb, wf1, wf2, b1, lng, lnb, b2, out);
}

// Round 21
// 140.597 us; speedup vs baseline: 1.0730x; 1.0730x over previous
//
#include <hip/hip_runtime.h>
#include <hip/hip_fp16.h>

#define N_NODES 100000
#define N_EDGES 1600000
#define DIM 128
#define NBUK 782      // ceil(N_NODES / 128), bucket = dst >> 7
#define EPB 4096      // edges per block in hist / scatter
#define NBLK 391      // ceil(N_EDGES / EPB)
#define NCNT (NBUK * NBLK)   // 305762 (bucket,block) counters
#define NSC 299       // ceil(NCNT / 1024) scan blocks
#define CAPB 2720     // max edges per bucket (mean 2048, +14 sigma)
#define CAPH 1536     // max edges per 64-node half-bucket
#define EPT 11        // max edges per thread in sort_gather (CAPB/256 = 10.6)

typedef __attribute__((ext_vector_type(4))) float f32x4;
typedef _Float16 h2 __attribute__((ext_vector_type(2)));
typedef _Float16 h8v __attribute__((ext_vector_type(8)));

__device__ __forceinline__ unsigned short f2h16(float f) {
    return __half_as_ushort(__float2half(f));
}

// ---------------------------------------------------------------------------
// 1) per-block bucket histogram + x->fp16 conversion (merged)
// ---------------------------------------------------------------------------
__global__ __launch_bounds__(256) void hist2_conv(
    const int* __restrict__ ei, int* __restrict__ cnts,
    const float* __restrict__ x, ushort* __restrict__ xh, int do_conv)
{
    __shared__ int cnt[NBUK];
    for (int i = threadIdx.x; i < NBUK; i += 256) cnt[i] = 0;

    if (do_conv) {
        for (int i = blockIdx.x * 256 + threadIdx.x; i < N_NODES * DIM / 4;
             i += NBLK * 256) {
            float4 v = ((const float4*)x)[i];
            ushort4 o;
            o.x = f2h16(v.x);
            o.y = f2h16(v.y);
            o.z = f2h16(v.z);
            o.w = f2h16(v.w);
            ((ushort4*)xh)[i] = o;
        }
    }
    __syncthreads();

    int e0 = blockIdx.x * EPB;
    int e1 = min(e0 + EPB, N_EDGES);
    for (int e = e0 + threadIdx.x; e < e1; e += 256)
        atomicAdd(&cnt[ei[N_EDGES + e] >> 7], 1);
    __syncthreads();
    for (int b = threadIdx.x; b < NBUK; b += 256)
        cnts[b * NBLK + blockIdx.x] = cnt[b];
}

// ---------------------------------------------------------------------------
// 2) scanA: per-1024-chunk exclusive scan, block sums -> bsums (raw)
// ---------------------------------------------------------------------------
__global__ __launch_bounds__(256) void scanA(
    int* __restrict__ cnts, int* __restrict__ bsums)
{
    __shared__ int s[256];
    int t = threadIdx.x;
    int base = blockIdx.x * 1024 + t * 4;
    int v0 = (base + 0 < NCNT) ? cnts[base + 0] : 0;
    int v1 = (base + 1 < NCNT) ? cnts[base + 1] : 0;
    int v2 = (base + 2 < NCNT) ? cnts[base + 2] : 0;
    int v3 = (base + 3 < NCNT) ? cnts[base + 3] : 0;
    int sum = v0 + v1 + v2 + v3;
    s[t] = sum;
    __syncthreads();
    for (int off = 1; off < 256; off <<= 1) {
        int x = (t >= off) ? s[t - off] : 0;
        __syncthreads();
        s[t] += x;
        __syncthreads();
    }
    int excl = s[t] - sum;
    if (base + 0 < NCNT) cnts[base + 0] = excl;  excl += v0;
    if (base + 1 < NCNT) cnts[base + 1] = excl;  excl += v1;
    if (base + 2 < NCNT) cnts[base + 2] = excl;  excl += v2;
    if (base + 3 < NCNT) cnts[base + 3] = excl;
    if (t == 255) bsums[blockIdx.x] = s[255];
}

// ---------------------------------------------------------------------------
// scanC + folded scanB + prep_w (fp16 fragment layout). 512 threads.
// ---------------------------------------------------------------------------
__global__ __launch_bounds__(512) void scanC_prepw(
    int* __restrict__ ebase, const int* __restrict__ bsums, int* __restrict__ bk,
    const float* __restrict__ W1, const float* __restrict__ W2,
    ushort* __restrict__ wf1, ushort* __restrict__ wf2)
{
    __shared__ int s[512];
    __shared__ int ex[512];
    int t = threadIdx.x;
    int v = (t < NSC) ? bsums[t] : 0;
    s[t] = v;
    __syncthreads();
    for (int off = 1; off < 512; off <<= 1) {
        int x = (t >= off) ? s[t - off] : 0;
        __syncthreads();
        s[t] += x;
        __syncthreads();
    }
    ex[t] = s[t] - v;   // exclusive prefix of bsums
    __syncthreads();

    int i = blockIdx.x * 512 + t;
    if (i < NCNT) {
        int val = ebase[i] + ex[i >> 10];
        ebase[i] = val;
        if (i % NBLK == 0) bk[i / NBLK] = val;   // bucket base
    }
    if (i == 0) bk[NBUK] = N_EDGES;

    if (i < DIM * DIM) {   // prep_w: fp16 fragment layout
        int lane = (i >> 3) & 63;
        int j = i & 7;
        int frag = i >> 9;
        int kt = frag >> 3, nt = frag & 7;
        int k = kt * 32 + (lane >> 4) * 8 + j;
        int n = nt * 16 + (lane & 15);
        wf1[i] = f2h16(W1[k * DIM + n]);
        wf2[i] = f2h16(W2[k * DIM + n]);
    }
}

// ---------------------------------------------------------------------------
// 3) scatter: payload = src | attr<<17 | dst_local<<19 (7 bits)
// ---------------------------------------------------------------------------
__global__ __launch_bounds__(256) void pass2_scatter(
    const int* __restrict__ ei, const int* __restrict__ ea,
    const int* __restrict__ ebase, int* __restrict__ ebuf)
{
    __shared__ int cnt[NBUK];
    __shared__ int mybase[NBUK];
    for (int i = threadIdx.x; i < NBUK; i += 256) {
        cnt[i] = 0;
        mybase[i] = ebase[i * NBLK + blockIdx.x];
    }
    __syncthreads();
    int e0 = blockIdx.x * EPB;
    int e1 = min(e0 + EPB, N_EDGES);
    for (int e = e0 + threadIdx.x; e < e1; e += 256) {
        int src = ei[e];
        int dst = ei[N_EDGES + e];
        int at  = ea[e];
        int pay = src | (at << 17) | ((dst & 127) << 19);
        int b   = dst >> 7;
        int r   = atomicAdd(&cnt[b], 1);
        ebuf[mybase[b] + r] = pay;
    }
}

// ---------------------------------------------------------------------------
// 4) FUSED per-bucket sort + gather: TWO 256-thread blocks per 128-node
// bucket, each handles one 64-node half (dst_local bit 6). ~8KB LDS.
// ---------------------------------------------------------------------------
template<int HI>
__device__ __forceinline__ float h2acc(h2 m2, float acc) {
#if __has_builtin(__builtin_amdgcn_fdot2)
    h2 b;
    b[0] = (_Float16)(HI ? 0.f : 1.f);
    b[1] = (_Float16)(HI ? 1.f : 0.f);
    return __builtin_amdgcn_fdot2(m2, b, acc, false);
#else
    return acc + (float)m2[HI];
#endif
}

__device__ __forceinline__ void edge_acc(
    int pkv, int c, const unsigned* embh, float* acc, uint4 xv)
{
    const uint4 ev = *(const uint4*)&embh[((((unsigned)pkv >> 17) & 3) << 6) | (c << 2)];
    unsigned xs[4] = {xv.x, xv.y, xv.z, xv.w};
    unsigned es[4] = {ev.x, ev.y, ev.z, ev.w};
    const h2 z2 = (h2)(_Float16)0;
    #pragma unroll
    for (int j = 0; j < 4; ++j) {
        h2 a = __builtin_bit_cast(h2, xs[j]);
        h2 b = __builtin_bit_cast(h2, es[j]);
        h2 m2 = __builtin_elementwise_max(a + b, z2);
        acc[2 * j]     = h2acc<0>(m2, acc[2 * j]);
        acc[2 * j + 1] = h2acc<1>(m2, acc[2 * j + 1]);
    }
}

template<int USE16>
__global__ __launch_bounds__(256) void sort_gather(
    const int* __restrict__ bk, const int* __restrict__ ebuf,
    const float* __restrict__ x, const ushort* __restrict__ xh,
    const float* __restrict__ emb, const float* __restrict__ eps_p,
    ushort* __restrict__ hb)
{
    __shared__ int col_l[CAPH];        // 6KB
    __shared__ int deg[64], sc[64], cur[64];
    __shared__ unsigned embh[256];     // 1KB (USE16)
    __shared__ float femb[512];        // 2KB (fallback)

    const int bb = blockIdx.x;
    const int b = bb >> 1;
    const int half = bb & 1;
    const int t = threadIdx.x;
    const int lo = bk[b];
    const int n_e = min(bk[b + 1] - lo, CAPB);

    {
        float2 f = ((const float2*)emb)[t];
        if (USE16) {
            __half2 h = __floats2half2_rn(f.x, f.y);
            embh[t] = __builtin_bit_cast(unsigned, h);
        } else {
            femb[2 * t] = f.x;
            femb[2 * t + 1] = f.y;
        }
    }
    if (t < 64) deg[t] = 0;
    __syncthreads();

    // stage this thread's edges (full bucket run), keep only my half
    int er[EPT];
    #pragma unroll
    for (int j = 0; j < EPT; ++j) {
        int i = t + j * 256;
        int pk = (i < n_e) ? ebuf[lo + i] : -1;
        if (pk != -1 && (int)(((unsigned)pk >> 25) & 1) != half) pk = -1;
        er[j] = pk;
    }

    // pass 1: histogram from registers (low 6 bits of dst_local)
    #pragma unroll
    for (int j = 0; j < EPT; ++j)
        if (er[j] != -1)
            atomicAdd(&deg[((unsigned)er[j] >> 19) & 63], 1);
    __syncthreads();

    if (t < 64) sc[t] = deg[t];
    __syncthreads();
    for (int off = 1; off < 64; off <<= 1) {
        int v = 0;
        if (t < 64 && t >= off) v = sc[t - off];
        __syncthreads();
        if (t < 64) sc[t] += v;
        __syncthreads();
    }
    if (t < 64) cur[t] = sc[t] - deg[t];
    __syncthreads();

    // pass 2: scatter from registers into node-sorted LDS list
    #pragma unroll
    for (int j = 0; j < EPT; ++j)
        if (er[j] != -1) {
            int p = atomicAdd(&cur[((unsigned)er[j] >> 19) & 63], 1);
            col_l[p] = er[j];
        }
    __syncthreads();

    // ---- gather: 16 groups x 16 lanes, 4 nodes per group ----
    const int g = t >> 4, c = t & 15;
    const float epsv = 1.0f + eps_p[0];

    for (int ln = g; ln < 64; ln += 16) {
        int n = b * 128 + half * 64 + ln;
        if (n >= N_NODES) break;
        int start = sc[ln] - deg[ln], end = sc[ln];
        float acc[8] = {0.f, 0.f, 0.f, 0.f, 0.f, 0.f, 0.f, 0.f};

        if (USE16) {
            int p = start;
            for (; p + 4 <= end; p += 4) {
                int pk[4];
                uint4 xv[4];
                #pragma unroll
                for (int u = 0; u < 4; ++u) pk[u] = col_l[p + u];
                #pragma unroll
                for (int u = 0; u < 4; ++u)
                    xv[u] = ((const uint4*)xh)[((pk[u] & 0x1FFFF) << 4) | c];
                #pragma unroll
                for (int u = 0; u < 4; ++u)
                    edge_acc(pk[u], c, embh, acc, xv[u]);
            }
            for (; p < end; ++p) {
                int pkv = col_l[p];
                uint4 xv = ((const uint4*)xh)[((pkv & 0x1FFFF) << 4) | c];
                edge_acc(pkv, c, embh, acc, xv);
            }
        } else {
            for (int p = start; p < end; ++p) {
                int pk = col_l[p];
                const float* xr = x + (size_t)(pk & 0x1FFFF) * DIM;
                float4 xa = ((const float4*)xr)[c * 2];
                float4 xb = ((const float4*)xr)[c * 2 + 1];
                const float* er2 = &femb[(((unsigned)pk >> 17) & 3) * DIM + c * 8];
                acc[0] += fmaxf(xa.x + er2[0], 0.f);
                acc[1] += fmaxf(xa.y + er2[1], 0.f);
                acc[2] += fmaxf(xa.z + er2[2], 0.f);
                acc[3] += fmaxf(xa.w + er2[3], 0.f);
                acc[4] += fmaxf(xb.x + er2[4], 0.f);
                acc[5] += fmaxf(xb.y + er2[5], 0.f);
                acc[6] += fmaxf(xb.z + er2[6], 0.f);
                acc[7] += fmaxf(xb.w + er2[7], 0.f);
            }
        }

        // self term: from fp16 xh (coalesced 16B read)
        float o[8];
        {
            uint4 xn = ((const uint4*)xh)[((unsigned)n << 4) | c];
            unsigned xs[4] = {xn.x, xn.y, xn.z, xn.w};
            #pragma unroll
            for (int j = 0; j < 4; ++j) {
                h2 a = __builtin_bit_cast(h2, xs[j]);
                o[2 * j]     = epsv * (float)a[0] + acc[2 * j];
                o[2 * j + 1] = epsv * (float)a[1] + acc[2 * j + 1];
            }
        }

        unsigned pw[4];
        #pragma unroll
        for (int j = 0; j < 4; ++j) {
            __half2 hh = __floats2half2_rn(o[2 * j], o[2 * j + 1]);
            pw[j] = __builtin_bit_cast(unsigned, hh);
        }
        ((uint4*)(hb + (size_t)n * DIM))[c] = make_uint4(pw[0], pw[1], pw[2], pw[3]);
    }
}

// ---------------------------------------------------------------------------
// Fused MLP via f16 MFMA: 64-node tile / 256-thread block, 80KB LDS -> 2/CU.
// ---------------------------------------------------------------------------
__global__ __launch_bounds__(256) void fused_mlp(
    const ushort* __restrict__ hb,
    const ushort* __restrict__ wf1, const ushort* __restrict__ wf2,
    const float* __restrict__ b1,
    const float* __restrict__ lng, const float* __restrict__ lnb,
    const float* __restrict__ b2,
    float* __restrict__ out)
{
    __shared__ ushort w1s[DIM * DIM];
    __shared__ ushort w2s[DIM * DIM];
    __shared__ ushort scr[4 * 16 * DIM];

    #pragma unroll
    for (int i = 0; i < 8; ++i) {
        int idx = i * 256 + threadIdx.x;
        ((uint4*)w1s)[idx] = ((const uint4*)wf1)[idx];
        ((uint4*)w2s)[idx] = ((const uint4*)wf2)[idx];
    }
    __syncthreads();

    const int w  = threadIdx.x >> 6;
    const int l  = threadIdx.x & 63;
    const int lc = l & 15;
    const int lr = l >> 4;

    const int rbase = blockIdx.x * 64 + w * 16;
    const int arow = min(rbase + lc, N_NODES - 1);
    const ushort* hp = hb + (size_t)arow * DIM;

    float g[8], bb[8], bi1[8], bi2[8];
    #pragma unroll
    for (int nt = 0; nt < 8; ++nt) {
        g[nt]  = lng[nt * 16 + lc];
        bb[nt] = lnb[nt * 16 + lc];
        bi1[nt] = b1[nt * 16 + lc];
        bi2[nt] = b2[nt * 16 + lc];
    }

    f32x4 acc[8];
    #pragma unroll
    for (int nt = 0; nt < 8; ++nt)
        acc[nt] = (f32x4){bi1[nt], bi1[nt], bi1[nt], bi1[nt]};

    #pragma unroll
    for (int kt = 0; kt < 4; ++kt) {
        h8v a = *(const h8v*)(hp + kt * 32 + lr * 8);
        #pragma unroll
        for (int nt = 0; nt < 8; ++nt) {
            h8v bf = *(const h8v*)&w1s[((kt * 8 + nt) * 64 + l) * 8];
            acc[nt] = __builtin_amdgcn_mfma_f32_16x16x32_f16(a, bf, acc[nt], 0, 0, 0);
        }
    }

    #pragma unroll
    for (int r = 0; r < 4; ++r) {
        float s1 = 0.f, s2 = 0.f;
        #pragma unroll
        for (int nt = 0; nt < 8; ++nt) { float v = acc[nt][r]; s1 += v; s2 += v * v; }
        s1 += __shfl_xor(s1, 1);  s2 += __shfl_xor(s2, 1);
        s1 += __shfl_xor(s1, 2);  s2 += __shfl_xor(s2, 2);
        s1 += __shfl_xor(s1, 4);  s2 += __shfl_xor(s2, 4);
        s1 += __shfl_xor(s1, 8);  s2 += __shfl_xor(s2, 8);
        float mu  = s1 * (1.0f / DIM);
        float var = s2 * (1.0f / DIM) - mu * mu;
        float rsd = rsqrtf(var + 1e-5f);
        int row = lr * 4 + r;
        #pragma unroll
        for (int nt = 0; nt < 8; ++nt) {
            float v = (acc[nt][r] - mu) * rsd * g[nt] + bb[nt];
            v = fmaxf(v, 0.f);
            int cidx = nt * 16 + lc;
            scr[w * 2048 + row * 128 + (((cidx >> 3) ^ row) << 3) + (cidx & 7)]
                = f2h16(v);
        }
    }

    f32x4 acc2[8];
    #pragma unroll
    for (int nt = 0; nt < 8; ++nt)
        acc2[nt] = (f32x4){bi2[nt], bi2[nt], bi2[nt], bi2[nt]};

    #pragma unroll
    for (int kt = 0; kt < 4; ++kt) {
        h8v a2 = *(const h8v*)&scr[w * 2048 + lc * 128 + (((kt * 4 + lr) ^ lc) << 3)];
        #pragma unroll
        for (int nt = 0; nt < 8; ++nt) {
            h8v bf = *(const h8v*)&w2s[((kt * 8 + nt) * 64 + l) * 8];
            acc2[nt] = __builtin_amdgcn_mfma_f32_16x16x32_f16(a2, bf, acc2[nt], 0, 0, 0);
        }
    }

    #pragma unroll
    for (int r = 0; r < 4; ++r) {
        int orow = rbase + lr * 4 + r;
        if (orow < N_NODES) {
            #pragma unroll
            for (int nt = 0; nt < 8; ++nt)
                out[(size_t)orow * DIM + nt * 16 + lc] = acc2[nt][r];
        }
    }
}

extern "C" void kernel_launch(void* const* d_in, const int* in_sizes, int n_in,
                              void* d_out, int out_size, void* d_ws, size_t ws_size,
                              hipStream_t stream) {
    const float* x    = (const float*)d_in[0];
    const int*   ei   = (const int*)d_in[1];
    const int*   ea   = (const int*)d_in[2];
    const float* emb  = (const float*)d_in[3];
    const float* epsp = (const float*)d_in[4];
    const float* W1   = (const float*)d_in[5];
    const float* b1   = (const float*)d_in[6];
    const float* lng  = (const float*)d_in[7];
    const float* lnb  = (const float*)d_in[8];
    const float* W2   = (const float*)d_in[9];
    const float* b2   = (const float*)d_in[10];
    float* out = (float*)d_out;

    // workspace layout (bytes)
    char* ws = (char*)d_ws;
    int* bk     = (int*)(ws);                 // [NBUK+1]
    int* bsums  = (int*)(ws + 4096);          // [NSC]
    ushort* wf1 = (ushort*)(ws + 8192);       // [16384] fp16 W1 frags
    ushort* wf2 = (ushort*)(ws + 40960);      // [16384] fp16 W2 frags
    int* cnts   = (int*)(ws + 81920);         // [NCNT] (scan in-place -> ebase)
    int* ebuf   = (int*)(ws + 1310720);       // [N_EDGES]
    ushort* hb  = (ushort*)(ws + 8025984);    // [N,128] fp16 h plane
    ushort* xh  = (ushort*)(ws + 59225984);   // [N,128] fp16 x
    const size_t NEED = 59225984 + (size_t)N_NODES * DIM * 2;   // ~84.8 MB

    const int use_f16 = (ws_size >= NEED) ? 1 : 0;

    hist2_conv<<<NBLK, 256, 0, stream>>>(ei, cnts, x, xh, use_f16);
    scanA<<<NSC, 256, 0, stream>>>(cnts, bsums);
    scanC_prepw<<<(NCNT + 511) / 512, 512, 0, stream>>>(
        cnts, bsums, bk, W1, W2, wf1, wf2);
    pass2_scatter<<<NBLK, 256, 0, stream>>>(ei, ea, cnts, ebuf);

    if (use_f16) {
        sort_gather<1><<<NBUK * 2, 256, 0, stream>>>(
            bk, ebuf, x, xh, emb, epsp, hb);
    } else {
        sort_gather<0><<<NBUK * 2, 256, 0, stream>>>(
            bk, ebuf, x, xh, emb, epsp, hb);
    }

    fused_mlp<<<(N_NODES + 63) / 64, 256, 0, stream>>>(
        hb, wf1, wf2, b1, lng, lnb, b2, out);
}